// Round 2
// baseline (331.177 us; speedup 1.0000x reference)
//
#include <hip/hip_runtime.h>
#include <cstdint>
#include <cstddef>

typedef __bf16 bf16;
typedef __bf16 v8bf __attribute__((ext_vector_type(8)));
typedef __bf16 v4bf __attribute__((ext_vector_type(4)));
typedef float  v4f  __attribute__((ext_vector_type(4)));

#define D_MODEL 1024
#define FF_DIM  4096
#define SEQ     2048
#define NTOK    4096   // B*S
#define NH      16
#define HDIM    64

#define GLOAD_LDS16(g, l) \
    __builtin_amdgcn_global_load_lds((const __attribute__((address_space(1))) void*)(g), \
                                     (__attribute__((address_space(3))) void*)(l), 16, 0, 0)

// q prescale: 1/8 * log2(e) so softmax uses raw exp2
#define QSCALE 0.18033688011112042f
// shift: -20 * log2(e)
#define SHIFT2 -28.853900817779268f

#define BARRIER()    asm volatile("s_barrier" ::: "memory")
#define WAIT_VM8()   asm volatile("s_waitcnt vmcnt(8)" ::: "memory")
#define WAIT_VM4()   asm volatile("s_waitcnt vmcnt(4)" ::: "memory")
#define WAIT_VM0()   asm volatile("s_waitcnt vmcnt(0)" ::: "memory")
#define WAIT_LGKM0() asm volatile("s_waitcnt lgkmcnt(0)" ::: "memory")

// ---------------- prep: all weight converts, one dispatch ------
__global__ __launch_bounds__(256) void prep_kernel(
    const float* __restrict__ Wqkv, const float* __restrict__ Wo,
    const float* __restrict__ W1, const float* __restrict__ W2,
    bf16* __restrict__ Wqkv_b, bf16* __restrict__ Wo_b,
    bf16* __restrict__ W1_b, bf16* __restrict__ W2_b) {
    int u = blockIdx.x * 256 + threadIdx.x;
    const float* src; bf16* dst; int idx;
    if (u < 786432)       { src = Wqkv; dst = Wqkv_b; idx = u * 4; }
    else if (u < 1048576) { src = Wo;   dst = Wo_b;   idx = (u - 786432) * 4; }
    else if (u < 2097152) { src = W1;   dst = W1_b;   idx = (u - 1048576) * 4; }
    else                  { src = W2;   dst = W2_b;   idx = (u - 2097152) * 4; }
    float4 v = *(const float4*)(src + idx);
    dst[idx + 0] = (bf16)v.x;
    dst[idx + 1] = (bf16)v.y;
    dst[idx + 2] = (bf16)v.z;
    dst[idx + 3] = (bf16)v.w;
}

// ---------------- LayerNorm (unbiased std, eps on std) ----------------
__global__ __launch_bounds__(256) void layernorm_kernel(
    const float* __restrict__ x, const float* __restrict__ scale,
    const float* __restrict__ shift, bf16* __restrict__ out) {
    int row = blockIdx.x;
    int t = threadIdx.x;
    const float* xr = x + (size_t)row * D_MODEL;
    float4 v = *(const float4*)(xr + t * 4);
    float s  = v.x + v.y + v.z + v.w;
    float sq = v.x * v.x + v.y * v.y + v.z * v.z + v.w * v.w;
    #pragma unroll
    for (int o = 1; o < 64; o <<= 1) {
        s  += __shfl_xor(s, o);
        sq += __shfl_xor(sq, o);
    }
    __shared__ float ws[8];
    int wv = t >> 6;
    if ((t & 63) == 0) { ws[wv * 2] = s; ws[wv * 2 + 1] = sq; }
    __syncthreads();
    s  = ws[0] + ws[2] + ws[4] + ws[6];
    sq = ws[1] + ws[3] + ws[5] + ws[7];
    float mean = s * (1.0f / D_MODEL);
    float var  = (sq - (float)D_MODEL * mean * mean) * (1.0f / (D_MODEL - 1));
    var = fmaxf(var, 0.0f);
    float inv = 1.0f / (sqrtf(var) + 1e-5f);
    #pragma unroll
    for (int j = 0; j < 4; ++j) {
        int c = t * 4 + j;
        float xv = (&v.x)[j];
        out[(size_t)row * D_MODEL + c] = (bf16)(shift[c] + scale[c] * (xv - mean) * inv);
    }
}

// ---------------- V transpose: [BH,S,HD] -> [BH,HD,S], 64x64 tiles ----------
__global__ __launch_bounds__(256) void transpose_v(
    const bf16* __restrict__ vb, bf16* __restrict__ vt) {
    int bh = blockIdx.x >> 5;
    int ts = blockIdx.x & 31;
    int t = threadIdx.x;
    __shared__ bf16 T[64][72];
    const bf16* src = vb + ((size_t)bh * SEQ + ts * 64) * HDIM;
    #pragma unroll
    for (int half = 0; half < 2; ++half) {
        int s = (t >> 3) + half * 32;
        int d0 = (t & 7) * 8;
        v8bf vv = *(const v8bf*)(src + (size_t)s * HDIM + d0);
        #pragma unroll
        for (int j = 0; j < 8; ++j) T[d0 + j][s] = vv[j];
    }
    __syncthreads();
    bf16* dst = vt + (size_t)bh * HDIM * SEQ + ts * 64;
    int d = t >> 2;
    #pragma unroll
    for (int cc = 0; cc < 2; ++cc) {
        int c = (t & 3) + cc * 4;
        v8bf o = *(const v8bf*)(&T[d][c * 8]);
        *(v8bf*)(dst + (size_t)d * SEQ + c * 8) = o;
    }
}

// ---------------- old 128x128 MFMA GEMM (kept for Wo: N=1024 needs 256 blocks)
// EPI 1: outf = resid + C + bias          (fp32 out)
template <int EPI>
__global__ __launch_bounds__(256) void gemm_nt(
    const bf16* __restrict__ A, const bf16* __restrict__ Bw,
    const float* __restrict__ bias, const float* __restrict__ resid,
    float* __restrict__ outf, bf16* __restrict__ ob0,
    bf16* __restrict__ ob1, bf16* __restrict__ ob2,
    int M, int N, int K, int klen) {
    __shared__ __align__(16) bf16 As[128 * 64];
    __shared__ __align__(16) bf16 Bs[128 * 64];
    int gx = gridDim.x;
    int lin = blockIdx.y * gx + blockIdx.x;
    int grpsz = 16 * gx;
    int group = lin / grpsz;
    int rem = lin - group * grpsz;
    int m_t = group * 16 + (rem & 15);
    int n_t = rem >> 4;
    int m0 = m_t * 128, n0 = n_t * 128;
    int kstart = blockIdx.z * klen;
    int t = threadIdx.x;
    int lane = t & 63, wave = t >> 6;
    int wm = wave >> 1, wn = wave & 1;
    int quad = lane >> 4, l16 = lane & 15;

    int srow8 = lane >> 3;
    int schunk = (lane & 7) ^ srow8;
    const bf16* agp = A  + (size_t)(m0 + wave * 8 + srow8) * K + kstart + schunk * 8;
    const bf16* bgp = Bw + (size_t)(n0 + wave * 8 + srow8) * K + kstart + schunk * 8;
    size_t row32 = (size_t)32 * K;

    v4f acc[4][4];
    #pragma unroll
    for (int i = 0; i < 4; ++i)
        #pragma unroll
        for (int j = 0; j < 4; ++j)
            acc[i][j] = (v4f){0.f, 0.f, 0.f, 0.f};

    int rsw = l16 & 7;
    for (int kk = 0; kk < klen; kk += 64) {
        __syncthreads();
        #pragma unroll
        for (int ii = 0; ii < 4; ++ii) {
            GLOAD_LDS16(agp + ii * row32 + kk, &As[ii * 2048 + wave * 512]);
            GLOAD_LDS16(bgp + ii * row32 + kk, &Bs[ii * 2048 + wave * 512]);
        }
        __syncthreads();
        #pragma unroll
        for (int h = 0; h < 2; ++h) {
            v8bf af[4], bfr[4];
            #pragma unroll
            for (int i = 0; i < 4; ++i)
                af[i] = *(const v8bf*)(&As[(wm * 64 + i * 16 + l16) * 64 + (((h * 4 + quad) ^ rsw)) * 8]);
            #pragma unroll
            for (int j = 0; j < 4; ++j)
                bfr[j] = *(const v8bf*)(&Bs[(wn * 64 + j * 16 + l16) * 64 + (((h * 4 + quad) ^ rsw)) * 8]);
            #pragma unroll
            for (int i = 0; i < 4; ++i)
                #pragma unroll
                for (int j = 0; j < 4; ++j)
                    acc[i][j] = __builtin_amdgcn_mfma_f32_16x16x32_bf16(af[i], bfr[j], acc[i][j], 0, 0, 0);
        }
    }

    #pragma unroll
    for (int i = 0; i < 4; ++i) {
        #pragma unroll
        for (int j = 0; j < 4; ++j) {
            #pragma unroll
            for (int r = 0; r < 4; ++r) {
                float v = acc[i][j][r];
                int row = m0 + wm * 64 + i * 16 + quad * 4 + r;
                int col = n0 + wn * 64 + j * 16 + l16;
                if (EPI == 1) {
                    size_t o = (size_t)row * N + col;
                    outf[o] = resid[o] + v + bias[col];
                }
            }
        }
    }
}

// ---------------- new 256x256 MFMA GEMM, counted-vmcnt pipelined ------------
template <int EPI>
__global__ __launch_bounds__(512, 2) void gemm2_nt(
    const bf16* __restrict__ A, const bf16* __restrict__ Bw,
    const float* __restrict__ bias, bf16* __restrict__ ob0,
    bf16* __restrict__ ob1, bf16* __restrict__ ob2,
    int M, int N, int K, int klen) {
    __shared__ __align__(16) bf16 smA[2][256 * 64];
    __shared__ __align__(16) bf16 smB[2][256 * 64];

    int m0 = blockIdx.y * 256, n0 = blockIdx.x * 256;
    int kstart = blockIdx.z * klen;
    int t = threadIdx.x;
    int lane = t & 63, wave = t >> 6;        // 8 waves
    int wm = wave >> 2, wn = wave & 3;       // 2 x 4 -> per-wave 128x64 of C
    int quad = lane >> 4, l16 = lane & 15;

    int srow8 = lane >> 3;
    int schunk = (lane & 7) ^ srow8;
    const bf16* aA = A  + (size_t)(m0 + wave * 8 + srow8) * K + kstart + schunk * 8;
    const bf16* bB = Bw + (size_t)(n0 + wave * 8 + srow8) * K + kstart + schunk * 8;
    size_t row64 = (size_t)64 * K;
    int NT = klen >> 6;

    v4f acc[8][4];
    #pragma unroll
    for (int i = 0; i < 8; ++i)
        #pragma unroll
        for (int j = 0; j < 4; ++j)
            acc[i][j] = (v4f){0.f, 0.f, 0.f, 0.f};

    auto stage = [&](int c, int kt) {
        size_t ko = (size_t)kt * 64;
        const bf16* ag = aA + ko;
        const bf16* bg = bB + ko;
        #pragma unroll
        for (int q = 0; q < 4; ++q) {
            GLOAD_LDS16(ag + q * row64, &smA[c][q * 4096 + wave * 512]);
            GLOAD_LDS16(bg + q * row64, &smB[c][q * 4096 + wave * 512]);
        }
    };

    stage(0, 0);
    if (NT > 1) { stage(1, 1); WAIT_VM8(); } else { WAIT_VM0(); }
    BARRIER();

    int rx = l16 & 7;
    int ch0 = (quad ^ rx) * 8;
    int ch1 = ch0 ^ 32;
    int arow = (wm * 128 + l16) * 64;
    int brow = (wn * 64 + l16) * 64;

    for (int kt = 0; kt < NT; ++kt) {
        int c = kt & 1;
        const bf16* Ab = &smA[c][arow];
        const bf16* Bb = &smB[c][brow];
        v8bf a[4][2], b[4][2];
        #pragma unroll
        for (int i = 0; i < 4; ++i) {
            a[i][0] = *(const v8bf*)(Ab + i * 1024 + ch0);
            a[i][1] = *(const v8bf*)(Ab + i * 1024 + ch1);
        }
        #pragma unroll
        for (int j = 0; j < 4; ++j) {
            b[j][0] = *(const v8bf*)(Bb + j * 1024 + ch0);
            b[j][1] = *(const v8bf*)(Bb + j * 1024 + ch1);
        }
        __builtin_amdgcn_s_setprio(1);
        #pragma unroll
        for (int i = 0; i < 4; ++i)
            #pragma unroll
            for (int j = 0; j < 2; ++j) {
                acc[i][j] = __builtin_amdgcn_mfma_f32_16x16x32_bf16(a[i][0], b[j][0], acc[i][j], 0, 0, 0);
                acc[i][j] = __builtin_amdgcn_mfma_f32_16x16x32_bf16(a[i][1], b[j][1], acc[i][j], 0, 0, 0);
            }
        __builtin_amdgcn_s_setprio(0);
        __builtin_amdgcn_s_setprio(1);
        #pragma unroll
        for (int i = 0; i < 4; ++i)
            #pragma unroll
            for (int j = 2; j < 4; ++j) {
                acc[i][j] = __builtin_amdgcn_mfma_f32_16x16x32_bf16(a[i][0], b[j][0], acc[i][j], 0, 0, 0);
                acc[i][j] = __builtin_amdgcn_mfma_f32_16x16x32_bf16(a[i][1], b[j][1], acc[i][j], 0, 0, 0);
            }
        __builtin_amdgcn_s_setprio(0);
        #pragma unroll
        for (int i = 0; i < 4; ++i) {
            a[i][0] = *(const v8bf*)(Ab + 4096 + i * 1024 + ch0);
            a[i][1] = *(const v8bf*)(Ab + 4096 + i * 1024 + ch1);
        }
        __builtin_amdgcn_s_setprio(1);
        #pragma unroll
        for (int i = 0; i < 4; ++i)
            #pragma unroll
            for (int j = 0; j < 2; ++j) {
                acc[i + 4][j] = __builtin_amdgcn_mfma_f32_16x16x32_bf16(a[i][0], b[j][0], acc[i + 4][j], 0, 0, 0);
                acc[i + 4][j] = __builtin_amdgcn_mfma_f32_16x16x32_bf16(a[i][1], b[j][1], acc[i + 4][j], 0, 0, 0);
            }
        __builtin_amdgcn_s_setprio(0);
        WAIT_LGKM0();
        BARRIER();
        if (kt + 2 < NT) stage(c, kt + 2);
        __builtin_amdgcn_s_setprio(1);
        #pragma unroll
        for (int i = 0; i < 4; ++i)
            #pragma unroll
            for (int j = 2; j < 4; ++j) {
                acc[i + 4][j] = __builtin_amdgcn_mfma_f32_16x16x32_bf16(a[i][0], b[j][0], acc[i + 4][j], 0, 0, 0);
                acc[i + 4][j] = __builtin_amdgcn_mfma_f32_16x16x32_bf16(a[i][1], b[j][1], acc[i + 4][j], 0, 0, 0);
            }
        __builtin_amdgcn_s_setprio(0);
        if (kt + 1 < NT) {
            if (kt + 2 < NT) WAIT_VM8();
            else             WAIT_VM0();
            BARRIER();
        }
    }

    #pragma unroll
    for (int i = 0; i < 8; ++i) {
        #pragma unroll
        for (int j = 0; j < 4; ++j) {
            #pragma unroll
            for (int r = 0; r < 4; ++r) {
                float v = acc[i][j][r];
                int row = m0 + wm * 128 + i * 16 + quad * 4 + r;
                int col = n0 + wn * 64 + j * 16 + l16;
                if (EPI == 0) {
                    int which = col >> 10, rr = col & 1023;
                    int h = rr >> 6, d = rr & 63;
                    int bb = row >> 11, sI = row & 2047;
                    size_t dst = (((size_t)(bb * NH + h)) * SEQ + sI) * HDIM + d;
                    if (which == 0)      ob0[dst] = (bf16)(v * QSCALE);
                    else if (which == 1) ob1[dst] = (bf16)v;
                    else                 ob2[dst] = (bf16)v;
                } else if (EPI == 2) {
                    float u = v + bias[col];
                    float y = 1.5957691216057308f * (u + 0.044715f * u * u * u);
                    float g = u * __builtin_amdgcn_rcpf(1.0f + __expf(-y));
                    ob0[(size_t)row * N + col] = (bf16)g;
                } else {   // EPI 6
                    ob0[(size_t)blockIdx.z * M * N + (size_t)row * N + col] = (bf16)v;
                }
            }
        }
    }
}

// ---------------- split-K=4 combine for W2: out = x1 + sum(p_z) + b2 --------
__global__ __launch_bounds__(256) void combine_w2(
    const bf16* __restrict__ part, const float* __restrict__ x1,
    const float* __restrict__ b2, float* __restrict__ out) {
    int i = (blockIdx.x * 256 + threadIdx.x) * 4;
    int col = i & (D_MODEL - 1);
    float4 xv = *(const float4*)(x1 + i);
    float4 bv = *(const float4*)(b2 + col);
    float4 r;
    r.x = xv.x + bv.x; r.y = xv.y + bv.y; r.z = xv.z + bv.z; r.w = xv.w + bv.w;
    #pragma unroll
    for (int z = 0; z < 4; ++z) {
        v4bf p = *(const v4bf*)(part + (size_t)z * NTOK * D_MODEL + i);
        r.x += (float)p[0]; r.y += (float)p[1]; r.z += (float)p[2]; r.w += (float)p[3];
    }
    *(float4*)(out + i) = r;
}

// ---------------- Flash attention: paired causal q-tiles ------
// Merged A/B processing: one ka/kc/vv LDS load feeds both q-fragments.
// K/V double-buffered with counted vmcnt (4 loads/thread per tile).
// P-scratch XOR-swizzled (sw = l16&12 on 4-elem chunks): conflict-free
// b64 writes and b128 reads (writer/reader share l16 -> same sw).
__device__ __forceinline__ void attn_tile_pair(
    int kv, int qwbA, int qwbB, bool doA, int quad, int l16, int sw,
    const bf16* Ks, const bf16* Vs, bf16* PwA, bf16* PwB,
    const v8bf& qfA0, const v8bf& qfA1, const v8bf& qfB0, const v8bf& qfB1,
    v4f (&oA)[4], v4f (&oB)[4], float& lA, float& lB) {
    #pragma unroll
    for (int hh = 0; hh < 2; ++hh) {
        int kb32 = kv + hh * 32;
        if (kb32 > qwbB + 15) break;              // B is the larger tile
        bool aH = doA && (kb32 <= qwbA + 15);     // wave-uniform
        #pragma unroll
        for (int j2 = 0; j2 < 2; ++j2) {
            int j = hh * 2 + j2;
            int kb16 = kb32 + j2 * 16;
            int key = j * 16 + l16;
            v8bf ka = *(const v8bf*)(&Ks[(key * 8 + (quad ^ (key & 7))) * 8]);
            v8bf kc = *(const v8bf*)(&Ks[(key * 8 + ((quad + 4) ^ (key & 7))) * 8]);
            int poff = l16 * 80 + ((j * 4 + quad) ^ sw) * 4;
            int keyb = kb16 + quad * 4;
            // ---- B fragment ----
            {
                union { bf16 h[4]; uint2 u; } pk;
                if (kb16 > qwbB + 15) {
                    pk.u = (uint2){0u, 0u};
                } else {
                    v4f s = (v4f){SHIFT2, SHIFT2, SHIFT2, SHIFT2};
                    s = __builtin_amdgcn_mfma_f32_16x16x32_bf16(ka, qfB0, s, 0, 0, 0);
                    s = __builtin_amdgcn_mfma_f32_16x16x32_bf16(kc, qfB1, s, 0, 0, 0);
                    bool dm = (kb16 + 15 > qwbB);
                    #pragma unroll
                    for (int r = 0; r < 4; ++r) {
                        float pv = __builtin_amdgcn_exp2f(s[r]);
                        if (dm) pv = (keyb + r <= qwbB + l16) ? pv : 0.f;
                        lB += pv;
                        pk.h[r] = (bf16)pv;
                    }
                }
                *(uint2*)(&PwB[poff]) = pk.u;
            }
            // ---- A fragment (shares ka/kc) ----
            if (aH) {
                union { bf16 h[4]; uint2 u; } pk;
                if (kb16 > qwbA + 15) {
                    pk.u = (uint2){0u, 0u};
                } else {
                    v4f s = (v4f){SHIFT2, SHIFT2, SHIFT2, SHIFT2};
                    s = __builtin_amdgcn_mfma_f32_16x16x32_bf16(ka, qfA0, s, 0, 0, 0);
                    s = __builtin_amdgcn_mfma_f32_16x16x32_bf16(kc, qfA1, s, 0, 0, 0);
                    bool dm = (kb16 + 15 > qwbA);
                    #pragma unroll
                    for (int r = 0; r < 4; ++r) {
                        float pv = __builtin_amdgcn_exp2f(s[r]);
                        if (dm) pv = (keyb + r <= qwbA + l16) ? pv : 0.f;
                        lA += pv;
                        pk.h[r] = (bf16)pv;
                    }
                }
                *(uint2*)(&PwA[poff]) = pk.u;
            }
        }
        int roff = l16 * 80 + (((hh * 4 + quad) * 2) ^ sw) * 4;
        v8bf pfB = *(const v8bf*)(&PwB[roff]);
        if (aH) {
            v8bf pfA = *(const v8bf*)(&PwA[roff]);
            #pragma unroll
            for (int dc = 0; dc < 4; ++dc) {
                int dim = dc * 16 + l16;
                v8bf vv = *(const v8bf*)(&Vs[(dim * 8 + ((quad + 4 * hh) ^ (dim & 7))) * 8]);
                oB[dc] = __builtin_amdgcn_mfma_f32_16x16x32_bf16(pfB, vv, oB[dc], 0, 0, 0);
                oA[dc] = __builtin_amdgcn_mfma_f32_16x16x32_bf16(pfA, vv, oA[dc], 0, 0, 0);
            }
        } else {
            #pragma unroll
            for (int dc = 0; dc < 4; ++dc) {
                int dim = dc * 16 + l16;
                v8bf vv = *(const v8bf*)(&Vs[(dim * 8 + ((quad + 4 * hh) ^ (dim & 7))) * 8]);
                oB[dc] = __builtin_amdgcn_mfma_f32_16x16x32_bf16(pfB, vv, oB[dc], 0, 0, 0);
            }
        }
    }
}

__global__ __launch_bounds__(256) void attn_kernel(
    const bf16* __restrict__ qb, const bf16* __restrict__ kb,
    const bf16* __restrict__ vt, bf16* __restrict__ ob) {
    int bh = blockIdx.x & 31;          // bh fastest -> same-XCD per head
    int pr = blockIdx.x >> 5;
    int qtA = pr, qtB = 31 - pr;

    int t = threadIdx.x;
    int wave = t >> 6, lane = t & 63;
    int quad = lane >> 4, l16 = lane & 15;
    int sw = l16 & 12;
    int qwbA = qtA * 64 + wave * 16;
    int qwbB = qtB * 64 + wave * 16;

    const bf16* Qh  = qb + (size_t)bh * SEQ * HDIM;
    const bf16* Kh  = kb + (size_t)bh * SEQ * HDIM;
    const bf16* Vth = vt + (size_t)bh * HDIM * SEQ;

    __shared__ __align__(16) bf16 Ks[2][64 * 64];
    __shared__ __align__(16) bf16 Vs[2][64 * 64];
    __shared__ __align__(16) bf16 Ps[4][2][16 * 80];
    bf16* PwA = &Ps[wave][0][0];
    bf16* PwB = &Ps[wave][1][0];

    int u0 = t, u1 = t + 256;
    int key0 = u0 >> 3, c0 = (u0 & 7) ^ (key0 & 7);
    int key1 = u1 >> 3, c1 = (u1 & 7) ^ (key1 & 7);
    const bf16* Ksrc0 = Kh + (size_t)key0 * HDIM + c0 * 8;
    const bf16* Ksrc1 = Kh + (size_t)key1 * HDIM + c1 * 8;
    const bf16* Vsrc0 = Vth + (size_t)key0 * SEQ + c0 * 8;
    const bf16* Vsrc1 = Vth + (size_t)key1 * SEQ + c1 * 8;

    auto stage = [&](int c, int kv) {
        GLOAD_LDS16(Ksrc0 + (size_t)kv * HDIM, &Ks[c][wave * 512]);
        GLOAD_LDS16(Ksrc1 + (size_t)kv * HDIM, &Ks[c][2048 + wave * 512]);
        GLOAD_LDS16(Vsrc0 + kv, &Vs[c][wave * 512]);
        GLOAD_LDS16(Vsrc1 + kv, &Vs[c][2048 + wave * 512]);
    };

    v8bf qfA0 = *(const v8bf*)(Qh + (size_t)(qwbA + l16) * HDIM + quad * 8);
    v8bf qfA1 = *(const v8bf*)(Qh + (size_t)(qwbA + l16) * HDIM + 32 + quad * 8);
    v8bf qfB0 = *(const v8bf*)(Qh + (size_t)(qwbB + l16) * HDIM + quad * 8);
    v8bf qfB1 = *(const v8bf*)(Qh + (size_t)(qwbB + l16) * HDIM + 32 + quad * 8);

    v4f oA[4], oB[4];
    #pragma unroll
    for (int dc = 0; dc < 4; ++dc) {
        oA[dc] = (v4f){0.f, 0.f, 0.f, 0.f};
        oB[dc] = (v4f){0.f, 0.f, 0.f, 0.f};
    }
    float lA = 0.f, lB = 0.f;

    int nt = qtB + 1;                  // staged kv-tiles (>= 17, so nt > 2)
    stage(0, 0);
    stage(1, 64);
    WAIT_VM4();
    BARRIER();

    for (int ti = 0; ti < nt; ++ti) {
        int c = ti & 1;
        int kv = ti * 64;
        bool doA = (ti <= qtA);
        attn_tile_pair(kv, qwbA, qwbB, doA, quad, l16, sw,
                       &Ks[c][0], &Vs[c][0], PwA, PwB,
                       qfA0, qfA1, qfB0, qfB1, oA, oB, lA, lB);
        WAIT_LGKM0();
        BARRIER();
        if (ti + 2 < nt) stage(c, kv + 128);
        if (ti + 1 < nt) {
            if (ti + 2 < nt) WAIT_VM4();
            else             WAIT_VM0();
            BARRIER();
        }
    }

    lA += __shfl_xor(lA, 16); lA += __shfl_xor(lA, 32);
    lB += __shfl_xor(lB, 16); lB += __shfl_xor(lB, 32);

    int b = bh >> 4, h = bh & 15;
    #pragma unroll
    for (int r = 0; r < 4; ++r) {
        float invA = 1.0f / __shfl(lA, quad * 4 + r);
        float invB = 1.0f / __shfl(lB, quad * 4 + r);
        int sA = qwbA + quad * 4 + r;
        int sB = qwbB + quad * 4 + r;
        #pragma unroll
        for (int dc = 0; dc < 4; ++dc) {
            int d = dc * 16 + l16;
            ob[((size_t)(b * SEQ + sA)) * D_MODEL + h * HDIM + d] = (bf16)(oA[dc][r] * invA);
            ob[((size_t)(b * SEQ + sB)) * D_MODEL + h * HDIM + d] = (bf16)(oB[dc][r] * invB);
        }
    }
}

// ---------------- launch ----------------
extern "C" void kernel_launch(void* const* d_in, const int* in_sizes, int n_in,
                              void* d_out, int out_size, void* d_ws, size_t ws_size,
                              hipStream_t stream) {
    const float* x      = (const float*)d_in[0];
    const float* scale1 = (const float*)d_in[1];
    const float* shift1 = (const float*)d_in[2];
    const float* Wqkv   = (const float*)d_in[3];
    const float* Wo_w   = (const float*)d_in[4];
    const float* Wo_b   = (const float*)d_in[5];
    const float* scale2 = (const float*)d_in[6];
    const float* shift2 = (const float*)d_in[7];
    const float* W1     = (const float*)d_in[8];
    const float* b1     = (const float*)d_in[9];
    const float* W2     = (const float*)d_in[10];
    const float* b2     = (const float*)d_in[11];
    float* out = (float*)d_out;

    char* ws = (char*)d_ws;
    size_t off = 0;
    auto alloc = [&](size_t bytes) -> char* {
        char* p = ws + off;
        off += (bytes + 255) & ~(size_t)255;
        return p;
    };
    bf16* Wqkv_b = (bf16*)alloc((size_t)3 * D_MODEL * D_MODEL * 2);
    bf16* Wo_bf  = (bf16*)alloc((size_t)D_MODEL * D_MODEL * 2);
    bf16* W1_b   = (bf16*)alloc((size_t)FF_DIM * D_MODEL * 2);
    bf16* W2_b   = (bf16*)alloc((size_t)D_MODEL * FF_DIM * 2);
    bf16* bufA   = (bf16*)alloc((size_t)NTOK * D_MODEL * 2);   // h1 / attn out / w2part[0]
    bf16* qb     = (bf16*)alloc((size_t)NTOK * D_MODEL * 2);   // q / h2 / w2part[1]
    bf16* kb     = (bf16*)alloc((size_t)NTOK * D_MODEL * 2);   // k / w2part[2]
    bf16* vb     = (bf16*)alloc((size_t)NTOK * D_MODEL * 2);   // v / w2part[3]
    bf16* vtb    = (bf16*)alloc((size_t)NTOK * D_MODEL * 2);   // V transposed
    float* x1    = (float*)alloc((size_t)NTOK * D_MODEL * 4);
    bf16* mbuf   = (bf16*)alloc((size_t)NTOK * FF_DIM * 2);
    bf16* w2part = bufA;   // 4 x 8.39 MB spans bufA..vb (all dead by W2)
    (void)ws_size; (void)n_in; (void)in_sizes; (void)out_size;

    prep_kernel<<<12288, 256, 0, stream>>>(Wqkv, Wo_w, W1, W2,
                                           Wqkv_b, Wo_bf, W1_b, W2_b);

    layernorm_kernel<<<NTOK, 256, 0, stream>>>(x, scale1, shift1, bufA);

    // merged QKV projection: N=3072, 256^2 pipelined kernel (192 blocks)
    gemm2_nt<0><<<dim3(3072 / 256, NTOK / 256), 512, 0, stream>>>(
        bufA, Wqkv_b, nullptr, qb, kb, vb, NTOK, 3072, D_MODEL, D_MODEL);

    transpose_v<<<1024, 256, 0, stream>>>(vb, vtb);

    attn_kernel<<<512, 256, 0, stream>>>(qb, kb, vtb, bufA);

    // Wo: x1 = x + attn*Wo^T + Wo_b   (old 128^2 kernel: N=1024 -> 256 blocks)
    gemm_nt<1><<<dim3(D_MODEL / 128, NTOK / 128), 256, 0, stream>>>(
        bufA, Wo_bf, Wo_b, x, x1, nullptr, nullptr, nullptr, NTOK, D_MODEL, D_MODEL, D_MODEL);

    layernorm_kernel<<<NTOK, 256, 0, stream>>>(x1, scale2, shift2, qb);

    // W1 + gelu: 256 blocks, one per CU
    gemm2_nt<2><<<dim3(FF_DIM / 256, NTOK / 256), 512, 0, stream>>>(
        qb, W1_b, b1, mbuf, nullptr, nullptr, NTOK, FF_DIM, D_MODEL, D_MODEL);

    // W2 split-K=4 (256 blocks), bf16 partials, then combine
    gemm2_nt<6><<<dim3(D_MODEL / 256, NTOK / 256, 4), 512, 0, stream>>>(
        mbuf, W2_b, nullptr, w2part, nullptr, nullptr, NTOK, D_MODEL, FF_DIM, FF_DIM / 4);

    combine_w2<<<NTOK * D_MODEL / 1024, 256, 0, stream>>>(w2part, x1, b2, out);
}

// Round 3
// 313.383 us; speedup vs baseline: 1.0568x; 1.0568x over previous
//
#include <hip/hip_runtime.h>
#include <cstdint>
#include <cstddef>

typedef __bf16 bf16;
typedef __bf16 v8bf __attribute__((ext_vector_type(8)));
typedef __bf16 v4bf __attribute__((ext_vector_type(4)));
typedef float  v4f  __attribute__((ext_vector_type(4)));

#define D_MODEL 1024
#define FF_DIM  4096
#define SEQ     2048
#define NTOK    4096   // B*S
#define NH      16
#define HDIM    64

#define GLOAD_LDS16(g, l) \
    __builtin_amdgcn_global_load_lds((const __attribute__((address_space(1))) void*)(g), \
                                     (__attribute__((address_space(3))) void*)(l), 16, 0, 0)

// q prescale: 1/8 * log2(e) so softmax uses raw exp2
#define QSCALE 0.18033688011112042f
// shift: -20 * log2(e)
#define SHIFT2 -28.853900817779268f

#define BARRIER()    asm volatile("s_barrier" ::: "memory")
#define WAIT_VM8()   asm volatile("s_waitcnt vmcnt(8)" ::: "memory")
#define WAIT_VM0()   asm volatile("s_waitcnt vmcnt(0)" ::: "memory")
#define WAIT_LGKM0() asm volatile("s_waitcnt lgkmcnt(0)" ::: "memory")

// ---------------- prep: all weight converts, one dispatch ------
__global__ __launch_bounds__(256) void prep_kernel(
    const float* __restrict__ Wqkv, const float* __restrict__ Wo,
    const float* __restrict__ W1, const float* __restrict__ W2,
    bf16* __restrict__ Wqkv_b, bf16* __restrict__ Wo_b,
    bf16* __restrict__ W1_b, bf16* __restrict__ W2_b) {
    int u = blockIdx.x * 256 + threadIdx.x;
    const float* src; bf16* dst; int idx;
    if (u < 786432)       { src = Wqkv; dst = Wqkv_b; idx = u * 4; }
    else if (u < 1048576) { src = Wo;   dst = Wo_b;   idx = (u - 786432) * 4; }
    else if (u < 2097152) { src = W1;   dst = W1_b;   idx = (u - 1048576) * 4; }
    else                  { src = W2;   dst = W2_b;   idx = (u - 2097152) * 4; }
    float4 v = *(const float4*)(src + idx);
    dst[idx + 0] = (bf16)v.x;
    dst[idx + 1] = (bf16)v.y;
    dst[idx + 2] = (bf16)v.z;
    dst[idx + 3] = (bf16)v.w;
}

// ---------------- LayerNorm (unbiased std, eps on std) ----------------
__global__ __launch_bounds__(256) void layernorm_kernel(
    const float* __restrict__ x, const float* __restrict__ scale,
    const float* __restrict__ shift, bf16* __restrict__ out) {
    int row = blockIdx.x;
    int t = threadIdx.x;
    const float* xr = x + (size_t)row * D_MODEL;
    float4 v = *(const float4*)(xr + t * 4);
    float s  = v.x + v.y + v.z + v.w;
    float sq = v.x * v.x + v.y * v.y + v.z * v.z + v.w * v.w;
    #pragma unroll
    for (int o = 1; o < 64; o <<= 1) {
        s  += __shfl_xor(s, o);
        sq += __shfl_xor(sq, o);
    }
    __shared__ float ws[8];
    int wv = t >> 6;
    if ((t & 63) == 0) { ws[wv * 2] = s; ws[wv * 2 + 1] = sq; }
    __syncthreads();
    s  = ws[0] + ws[2] + ws[4] + ws[6];
    sq = ws[1] + ws[3] + ws[5] + ws[7];
    float mean = s * (1.0f / D_MODEL);
    float var  = (sq - (float)D_MODEL * mean * mean) * (1.0f / (D_MODEL - 1));
    var = fmaxf(var, 0.0f);
    float inv = 1.0f / (sqrtf(var) + 1e-5f);
    #pragma unroll
    for (int j = 0; j < 4; ++j) {
        int c = t * 4 + j;
        float xv = (&v.x)[j];
        out[(size_t)row * D_MODEL + c] = (bf16)(shift[c] + scale[c] * (xv - mean) * inv);
    }
}

// ---------------- V transpose: [BH,S,HD] -> [BH,HD,S], 64x64 tiles ----------
__global__ __launch_bounds__(256) void transpose_v(
    const bf16* __restrict__ vb, bf16* __restrict__ vt) {
    int bh = blockIdx.x >> 5;
    int ts = blockIdx.x & 31;
    int t = threadIdx.x;
    __shared__ bf16 T[64][72];
    const bf16* src = vb + ((size_t)bh * SEQ + ts * 64) * HDIM;
    #pragma unroll
    for (int half = 0; half < 2; ++half) {
        int s = (t >> 3) + half * 32;
        int d0 = (t & 7) * 8;
        v8bf vv = *(const v8bf*)(src + (size_t)s * HDIM + d0);
        #pragma unroll
        for (int j = 0; j < 8; ++j) T[d0 + j][s] = vv[j];
    }
    __syncthreads();
    bf16* dst = vt + (size_t)bh * HDIM * SEQ + ts * 64;
    int d = t >> 2;
    #pragma unroll
    for (int cc = 0; cc < 2; ++cc) {
        int c = (t & 3) + cc * 4;
        v8bf o = *(const v8bf*)(&T[d][c * 8]);
        *(v8bf*)(dst + (size_t)d * SEQ + c * 8) = o;
    }
}

// ---------------- old 128x128 MFMA GEMM (kept for Wo: N=1024 needs 256 blocks)
// EPI 1: outf = resid + C + bias          (fp32 out)
template <int EPI>
__global__ __launch_bounds__(256) void gemm_nt(
    const bf16* __restrict__ A, const bf16* __restrict__ Bw,
    const float* __restrict__ bias, const float* __restrict__ resid,
    float* __restrict__ outf, bf16* __restrict__ ob0,
    bf16* __restrict__ ob1, bf16* __restrict__ ob2,
    int M, int N, int K, int klen) {
    __shared__ __align__(16) bf16 As[128 * 64];
    __shared__ __align__(16) bf16 Bs[128 * 64];
    int gx = gridDim.x;
    int lin = blockIdx.y * gx + blockIdx.x;
    int grpsz = 16 * gx;
    int group = lin / grpsz;
    int rem = lin - group * grpsz;
    int m_t = group * 16 + (rem & 15);
    int n_t = rem >> 4;
    int m0 = m_t * 128, n0 = n_t * 128;
    int kstart = blockIdx.z * klen;
    int t = threadIdx.x;
    int lane = t & 63, wave = t >> 6;
    int wm = wave >> 1, wn = wave & 1;
    int quad = lane >> 4, l16 = lane & 15;

    int srow8 = lane >> 3;
    int schunk = (lane & 7) ^ srow8;
    const bf16* agp = A  + (size_t)(m0 + wave * 8 + srow8) * K + kstart + schunk * 8;
    const bf16* bgp = Bw + (size_t)(n0 + wave * 8 + srow8) * K + kstart + schunk * 8;
    size_t row32 = (size_t)32 * K;

    v4f acc[4][4];
    #pragma unroll
    for (int i = 0; i < 4; ++i)
        #pragma unroll
        for (int j = 0; j < 4; ++j)
            acc[i][j] = (v4f){0.f, 0.f, 0.f, 0.f};

    int rsw = l16 & 7;
    for (int kk = 0; kk < klen; kk += 64) {
        __syncthreads();
        #pragma unroll
        for (int ii = 0; ii < 4; ++ii) {
            GLOAD_LDS16(agp + ii * row32 + kk, &As[ii * 2048 + wave * 512]);
            GLOAD_LDS16(bgp + ii * row32 + kk, &Bs[ii * 2048 + wave * 512]);
        }
        __syncthreads();
        #pragma unroll
        for (int h = 0; h < 2; ++h) {
            v8bf af[4], bfr[4];
            #pragma unroll
            for (int i = 0; i < 4; ++i)
                af[i] = *(const v8bf*)(&As[(wm * 64 + i * 16 + l16) * 64 + (((h * 4 + quad) ^ rsw)) * 8]);
            #pragma unroll
            for (int j = 0; j < 4; ++j)
                bfr[j] = *(const v8bf*)(&Bs[(wn * 64 + j * 16 + l16) * 64 + (((h * 4 + quad) ^ rsw)) * 8]);
            #pragma unroll
            for (int i = 0; i < 4; ++i)
                #pragma unroll
                for (int j = 0; j < 4; ++j)
                    acc[i][j] = __builtin_amdgcn_mfma_f32_16x16x32_bf16(af[i], bfr[j], acc[i][j], 0, 0, 0);
        }
    }

    #pragma unroll
    for (int i = 0; i < 4; ++i) {
        #pragma unroll
        for (int j = 0; j < 4; ++j) {
            #pragma unroll
            for (int r = 0; r < 4; ++r) {
                float v = acc[i][j][r];
                int row = m0 + wm * 64 + i * 16 + quad * 4 + r;
                int col = n0 + wn * 64 + j * 16 + l16;
                if (EPI == 1) {
                    size_t o = (size_t)row * N + col;
                    outf[o] = resid[o] + v + bias[col];
                }
            }
        }
    }
}

// ---------------- new 256x256 MFMA GEMM, counted-vmcnt pipelined ------------
template <int EPI>
__global__ __launch_bounds__(512, 2) void gemm2_nt(
    const bf16* __restrict__ A, const bf16* __restrict__ Bw,
    const float* __restrict__ bias, bf16* __restrict__ ob0,
    bf16* __restrict__ ob1, bf16* __restrict__ ob2,
    int M, int N, int K, int klen) {
    __shared__ __align__(16) bf16 smA[2][256 * 64];
    __shared__ __align__(16) bf16 smB[2][256 * 64];

    int m0 = blockIdx.y * 256, n0 = blockIdx.x * 256;
    int kstart = blockIdx.z * klen;
    int t = threadIdx.x;
    int lane = t & 63, wave = t >> 6;        // 8 waves
    int wm = wave >> 2, wn = wave & 3;       // 2 x 4 -> per-wave 128x64 of C
    int quad = lane >> 4, l16 = lane & 15;

    int srow8 = lane >> 3;
    int schunk = (lane & 7) ^ srow8;
    const bf16* aA = A  + (size_t)(m0 + wave * 8 + srow8) * K + kstart + schunk * 8;
    const bf16* bB = Bw + (size_t)(n0 + wave * 8 + srow8) * K + kstart + schunk * 8;
    size_t row64 = (size_t)64 * K;
    int NT = klen >> 6;

    v4f acc[8][4];
    #pragma unroll
    for (int i = 0; i < 8; ++i)
        #pragma unroll
        for (int j = 0; j < 4; ++j)
            acc[i][j] = (v4f){0.f, 0.f, 0.f, 0.f};

    auto stage = [&](int c, int kt) {
        size_t ko = (size_t)kt * 64;
        const bf16* ag = aA + ko;
        const bf16* bg = bB + ko;
        #pragma unroll
        for (int q = 0; q < 4; ++q) {
            GLOAD_LDS16(ag + q * row64, &smA[c][q * 4096 + wave * 512]);
            GLOAD_LDS16(bg + q * row64, &smB[c][q * 4096 + wave * 512]);
        }
    };

    stage(0, 0);
    if (NT > 1) { stage(1, 1); WAIT_VM8(); } else { WAIT_VM0(); }
    BARRIER();

    int rx = l16 & 7;
    int ch0 = (quad ^ rx) * 8;
    int ch1 = ch0 ^ 32;
    int arow = (wm * 128 + l16) * 64;
    int brow = (wn * 64 + l16) * 64;

    for (int kt = 0; kt < NT; ++kt) {
        int c = kt & 1;
        const bf16* Ab = &smA[c][arow];
        const bf16* Bb = &smB[c][brow];
        v8bf a[4][2], b[4][2];
        #pragma unroll
        for (int i = 0; i < 4; ++i) {
            a[i][0] = *(const v8bf*)(Ab + i * 1024 + ch0);
            a[i][1] = *(const v8bf*)(Ab + i * 1024 + ch1);
        }
        #pragma unroll
        for (int j = 0; j < 4; ++j) {
            b[j][0] = *(const v8bf*)(Bb + j * 1024 + ch0);
            b[j][1] = *(const v8bf*)(Bb + j * 1024 + ch1);
        }
        __builtin_amdgcn_s_setprio(1);
        #pragma unroll
        for (int i = 0; i < 4; ++i)
            #pragma unroll
            for (int j = 0; j < 2; ++j) {
                acc[i][j] = __builtin_amdgcn_mfma_f32_16x16x32_bf16(a[i][0], b[j][0], acc[i][j], 0, 0, 0);
                acc[i][j] = __builtin_amdgcn_mfma_f32_16x16x32_bf16(a[i][1], b[j][1], acc[i][j], 0, 0, 0);
            }
        __builtin_amdgcn_s_setprio(0);
        __builtin_amdgcn_s_setprio(1);
        #pragma unroll
        for (int i = 0; i < 4; ++i)
            #pragma unroll
            for (int j = 2; j < 4; ++j) {
                acc[i][j] = __builtin_amdgcn_mfma_f32_16x16x32_bf16(a[i][0], b[j][0], acc[i][j], 0, 0, 0);
                acc[i][j] = __builtin_amdgcn_mfma_f32_16x16x32_bf16(a[i][1], b[j][1], acc[i][j], 0, 0, 0);
            }
        __builtin_amdgcn_s_setprio(0);
        #pragma unroll
        for (int i = 0; i < 4; ++i) {
            a[i][0] = *(const v8bf*)(Ab + 4096 + i * 1024 + ch0);
            a[i][1] = *(const v8bf*)(Ab + 4096 + i * 1024 + ch1);
        }
        __builtin_amdgcn_s_setprio(1);
        #pragma unroll
        for (int i = 0; i < 4; ++i)
            #pragma unroll
            for (int j = 0; j < 2; ++j) {
                acc[i + 4][j] = __builtin_amdgcn_mfma_f32_16x16x32_bf16(a[i][0], b[j][0], acc[i + 4][j], 0, 0, 0);
                acc[i + 4][j] = __builtin_amdgcn_mfma_f32_16x16x32_bf16(a[i][1], b[j][1], acc[i + 4][j], 0, 0, 0);
            }
        __builtin_amdgcn_s_setprio(0);
        WAIT_LGKM0();
        BARRIER();
        if (kt + 2 < NT) stage(c, kt + 2);
        __builtin_amdgcn_s_setprio(1);
        #pragma unroll
        for (int i = 0; i < 4; ++i)
            #pragma unroll
            for (int j = 2; j < 4; ++j) {
                acc[i + 4][j] = __builtin_amdgcn_mfma_f32_16x16x32_bf16(a[i][0], b[j][0], acc[i + 4][j], 0, 0, 0);
                acc[i + 4][j] = __builtin_amdgcn_mfma_f32_16x16x32_bf16(a[i][1], b[j][1], acc[i + 4][j], 0, 0, 0);
            }
        __builtin_amdgcn_s_setprio(0);
        if (kt + 1 < NT) {
            if (kt + 2 < NT) WAIT_VM8();
            else             WAIT_VM0();
            BARRIER();
        }
    }

    #pragma unroll
    for (int i = 0; i < 8; ++i) {
        #pragma unroll
        for (int j = 0; j < 4; ++j) {
            #pragma unroll
            for (int r = 0; r < 4; ++r) {
                float v = acc[i][j][r];
                int row = m0 + wm * 128 + i * 16 + quad * 4 + r;
                int col = n0 + wn * 64 + j * 16 + l16;
                if (EPI == 0) {
                    int which = col >> 10, rr = col & 1023;
                    int h = rr >> 6, d = rr & 63;
                    int bb = row >> 11, sI = row & 2047;
                    size_t dst = (((size_t)(bb * NH + h)) * SEQ + sI) * HDIM + d;
                    if (which == 0)      ob0[dst] = (bf16)(v * QSCALE);
                    else if (which == 1) ob1[dst] = (bf16)v;
                    else                 ob2[dst] = (bf16)v;
                } else if (EPI == 2) {
                    float u = v + bias[col];
                    float y = 1.5957691216057308f * (u + 0.044715f * u * u * u);
                    float g = u * __builtin_amdgcn_rcpf(1.0f + __expf(-y));
                    ob0[(size_t)row * N + col] = (bf16)g;
                } else {   // EPI 6
                    ob0[(size_t)blockIdx.z * M * N + (size_t)row * N + col] = (bf16)v;
                }
            }
        }
    }
}

// ---------------- split-K=4 combine for W2: out = x1 + sum(p_z) + b2 --------
__global__ __launch_bounds__(256) void combine_w2(
    const bf16* __restrict__ part, const float* __restrict__ x1,
    const float* __restrict__ b2, float* __restrict__ out) {
    int i = (blockIdx.x * 256 + threadIdx.x) * 4;
    int col = i & (D_MODEL - 1);
    float4 xv = *(const float4*)(x1 + i);
    float4 bv = *(const float4*)(b2 + col);
    float4 r;
    r.x = xv.x + bv.x; r.y = xv.y + bv.y; r.z = xv.z + bv.z; r.w = xv.w + bv.w;
    #pragma unroll
    for (int z = 0; z < 4; ++z) {
        v4bf p = *(const v4bf*)(part + (size_t)z * NTOK * D_MODEL + i);
        r.x += (float)p[0]; r.y += (float)p[1]; r.z += (float)p[2]; r.w += (float)p[3];
    }
    *(float4*)(out + i) = r;
}

// ---------------- Flash attention: paired causal q-tiles, kv-split ---------
// 512 threads = 8 waves: group g = wave>>2 takes kv-tiles with parity g;
// wv = wave&3 is the 16-row q strip. Row-sum via ones-column MFMA (o5):
// out[qrow][*] all-equal row sum -> no cross-lane reduction, no VALU adds.
// Partials combined through LDS scratch at the end.
__device__ __forceinline__ void attn_process_tile(
    int kv, int qwb, int quad, int l16,
    const bf16* Ks, const bf16* Vs, bf16* Pw, const v8bf& ones,
    const v8bf& qf0, const v8bf& qf1, v4f (&o)[4], v4f& o5) {
    #pragma unroll
    for (int hh = 0; hh < 2; ++hh) {
        int kb32 = kv + hh * 32;
        if (kb32 > qwb + 15) break;          // half fully above diagonal
        #pragma unroll
        for (int j2 = 0; j2 < 2; ++j2) {
            int j = hh * 2 + j2;
            int kb16 = kb32 + j2 * 16;
            union { bf16 h[4]; uint2 u; } pk;
            if (kb16 > qwb + 15) {
                pk.u = (uint2){0u, 0u};      // fully-masked sub-tile: zero-fill
            } else {
                int key = j * 16 + l16;
                v8bf ka = *(const v8bf*)(&Ks[(key * 8 + (quad ^ (key & 7))) * 8]);
                v8bf kc = *(const v8bf*)(&Ks[(key * 8 + ((quad + 4) ^ (key & 7))) * 8]);
                v4f s = (v4f){SHIFT2, SHIFT2, SHIFT2, SHIFT2};
                s = __builtin_amdgcn_mfma_f32_16x16x32_bf16(ka, qf0, s, 0, 0, 0);
                s = __builtin_amdgcn_mfma_f32_16x16x32_bf16(kc, qf1, s, 0, 0, 0);
                bool dm = (kb16 + 15 > qwb);  // straddles diagonal
                int keyb = kb16 + quad * 4;
                #pragma unroll
                for (int r = 0; r < 4; ++r) {
                    float pv = __builtin_amdgcn_exp2f(s[r]);
                    if (dm) pv = (keyb + r <= qwb + l16) ? pv : 0.f;
                    pk.h[r] = (bf16)pv;
                }
            }
            *(uint2*)(&Pw[l16 * 80 + j * 16 + quad * 4]) = pk.u;
        }
        v8bf pf = *(const v8bf*)(&Pw[l16 * 80 + hh * 32 + quad * 8]);
        o5 = __builtin_amdgcn_mfma_f32_16x16x32_bf16(pf, ones, o5, 0, 0, 0);
        #pragma unroll
        for (int dc = 0; dc < 4; ++dc) {
            int dim = dc * 16 + l16;
            v8bf vv = *(const v8bf*)(&Vs[(dim * 8 + ((quad + 4 * hh) ^ (dim & 7))) * 8]);
            o[dc] = __builtin_amdgcn_mfma_f32_16x16x32_bf16(pf, vv, o[dc], 0, 0, 0);
        }
    }
}

__global__ __launch_bounds__(512, 4) void attn_kernel(
    const bf16* __restrict__ qb, const bf16* __restrict__ kb,
    const bf16* __restrict__ vt, bf16* __restrict__ ob) {
    int bh = blockIdx.x & 31;          // bh fastest -> same-XCD per head
    int pr = blockIdx.x >> 5;
    int qtA = pr, qtB = 31 - pr;

    int t = threadIdx.x;
    int wave = t >> 6, lane = t & 63;
    int g = wave >> 2, wv = wave & 3;  // kv-parity group, q-row strip
    int quad = lane >> 4, l16 = lane & 15;
    int qwbA = qtA * 64 + wv * 16;
    int qwbB = qtB * 64 + wv * 16;

    const bf16* Qh  = qb + (size_t)bh * SEQ * HDIM;
    const bf16* Kh  = kb + (size_t)bh * SEQ * HDIM;
    const bf16* Vth = vt + (size_t)bh * HDIM * SEQ;

    // LDS: Ks[2][4096] | Vs[2][4096] | Ps[8][1280]  (53248 B); scr overlays.
    __shared__ __align__(16) char smem_raw[53248];
    bf16* Ks  = (bf16*)smem_raw;
    bf16* Vs  = (bf16*)(smem_raw + 16384);
    bf16* Pw  = (bf16*)(smem_raw + 32768) + wave * 1280;
    float* scr = (float*)smem_raw;

    // staging: 512 threads x 16B = one 8KB tile per instruction
    int key = t >> 3;
    int cch = (t & 7) ^ (key & 7);
    const bf16* Ksrc = Kh + (size_t)key * HDIM + cch * 8;
    const bf16* Vsrc = Vth + (size_t)key * SEQ + cch * 8;
    bf16* kdst0 = Ks + wave * 512;
    bf16* kdst1 = Ks + 4096 + wave * 512;
    bf16* vdst0 = Vs + wave * 512;
    bf16* vdst1 = Vs + 4096 + wave * 512;

    v8bf qfA0 = *(const v8bf*)(Qh + (size_t)(qwbA + l16) * HDIM + quad * 8);
    v8bf qfA1 = *(const v8bf*)(Qh + (size_t)(qwbA + l16) * HDIM + 32 + quad * 8);
    v8bf qfB0 = *(const v8bf*)(Qh + (size_t)(qwbB + l16) * HDIM + quad * 8);
    v8bf qfB1 = *(const v8bf*)(Qh + (size_t)(qwbB + l16) * HDIM + 32 + quad * 8);

    v8bf ones;
    #pragma unroll
    for (int j = 0; j < 8; ++j) ones[j] = (bf16)1.0f;

    v4f oA[4], oB[4];
    #pragma unroll
    for (int dc = 0; dc < 4; ++dc) {
        oA[dc] = (v4f){0.f, 0.f, 0.f, 0.f};
        oB[dc] = (v4f){0.f, 0.f, 0.f, 0.f};
    }
    v4f o5A = (v4f){0.f, 0.f, 0.f, 0.f};
    v4f o5B = (v4f){0.f, 0.f, 0.f, 0.f};

    int nt = qtB + 1;                  // kv tiles (17..32)
    int nit = (nt + 1) >> 1;
    for (int it = 0; it < nit; ++it) {
        int t0 = 2 * it;
        int t1 = t0 + 1;
        __syncthreads();               // previous compute done
        GLOAD_LDS16(Ksrc + (size_t)(t0 * 64) * HDIM, kdst0);
        GLOAD_LDS16(Vsrc + t0 * 64, vdst0);
        if (t1 < nt) {
            GLOAD_LDS16(Ksrc + (size_t)(t1 * 64) * HDIM, kdst1);
            GLOAD_LDS16(Vsrc + t1 * 64, vdst1);
        }
        __syncthreads();               // drains vmcnt, publishes both bufs
        int ti = t0 + g;
        if (ti < nt) {
            int kv = ti * 64;
            const bf16* Kst = Ks + g * 4096;
            const bf16* Vst = Vs + g * 4096;
            if (ti <= qtA)
                attn_process_tile(kv, qwbA, quad, l16, Kst, Vst, Pw, ones,
                                  qfA0, qfA1, oA, o5A);
            attn_process_tile(kv, qwbB, quad, l16, Kst, Vst, Pw, ones,
                              qfB0, qfB1, oB, o5B);
        }
    }

    // ---- combine group partials through LDS scratch ----
    __syncthreads();
    int sbase = wv * 2560 + lane;
    if (g == 1) {
        #pragma unroll
        for (int dc = 0; dc < 4; ++dc)
            #pragma unroll
            for (int r = 0; r < 4; ++r) {
                scr[sbase + (dc * 4 + r) * 64]        = oA[dc][r];
                scr[sbase + (16 + dc * 4 + r) * 64]   = oB[dc][r];
            }
        #pragma unroll
        for (int r = 0; r < 4; ++r) {
            scr[sbase + (32 + r) * 64] = o5A[r];
            scr[sbase + (36 + r) * 64] = o5B[r];
        }
    }
    __syncthreads();
    if (g == 0) {
        #pragma unroll
        for (int dc = 0; dc < 4; ++dc)
            #pragma unroll
            for (int r = 0; r < 4; ++r) {
                oA[dc][r] += scr[sbase + (dc * 4 + r) * 64];
                oB[dc][r] += scr[sbase + (16 + dc * 4 + r) * 64];
            }
        #pragma unroll
        for (int r = 0; r < 4; ++r) {
            o5A[r] += scr[sbase + (32 + r) * 64];
            o5B[r] += scr[sbase + (36 + r) * 64];
        }
        int b = bh >> 4, h = bh & 15;
        #pragma unroll
        for (int r = 0; r < 4; ++r) {
            float invA = 1.0f / o5A[r];
            float invB = 1.0f / o5B[r];
            int sA = qwbA + quad * 4 + r;
            int sB = qwbB + quad * 4 + r;
            #pragma unroll
            for (int dc = 0; dc < 4; ++dc) {
                int d = dc * 16 + l16;
                ob[((size_t)(b * SEQ + sA)) * D_MODEL + h * HDIM + d] = (bf16)(oA[dc][r] * invA);
                ob[((size_t)(b * SEQ + sB)) * D_MODEL + h * HDIM + d] = (bf16)(oB[dc][r] * invB);
            }
        }
    }
}

// ---------------- launch ----------------
extern "C" void kernel_launch(void* const* d_in, const int* in_sizes, int n_in,
                              void* d_out, int out_size, void* d_ws, size_t ws_size,
                              hipStream_t stream) {
    const float* x      = (const float*)d_in[0];
    const float* scale1 = (const float*)d_in[1];
    const float* shift1 = (const float*)d_in[2];
    const float* Wqkv   = (const float*)d_in[3];
    const float* Wo_w   = (const float*)d_in[4];
    const float* Wo_b   = (const float*)d_in[5];
    const float* scale2 = (const float*)d_in[6];
    const float* shift2 = (const float*)d_in[7];
    const float* W1     = (const float*)d_in[8];
    const float* b1     = (const float*)d_in[9];
    const float* W2     = (const float*)d_in[10];
    const float* b2     = (const float*)d_in[11];
    float* out = (float*)d_out;

    char* ws = (char*)d_ws;
    size_t off = 0;
    auto alloc = [&](size_t bytes) -> char* {
        char* p = ws + off;
        off += (bytes + 255) & ~(size_t)255;
        return p;
    };
    bf16* Wqkv_b = (bf16*)alloc((size_t)3 * D_MODEL * D_MODEL * 2);
    bf16* Wo_bf  = (bf16*)alloc((size_t)D_MODEL * D_MODEL * 2);
    bf16* W1_b   = (bf16*)alloc((size_t)FF_DIM * D_MODEL * 2);
    bf16* W2_b   = (bf16*)alloc((size_t)D_MODEL * FF_DIM * 2);
    bf16* bufA   = (bf16*)alloc((size_t)NTOK * D_MODEL * 2);   // h1 / attn out / w2part[0]
    bf16* qb     = (bf16*)alloc((size_t)NTOK * D_MODEL * 2);   // q / h2 / w2part[1]
    bf16* kb     = (bf16*)alloc((size_t)NTOK * D_MODEL * 2);   // k / w2part[2]
    bf16* vb     = (bf16*)alloc((size_t)NTOK * D_MODEL * 2);   // v / w2part[3]
    bf16* vtb    = (bf16*)alloc((size_t)NTOK * D_MODEL * 2);   // V transposed
    float* x1    = (float*)alloc((size_t)NTOK * D_MODEL * 4);
    bf16* mbuf   = (bf16*)alloc((size_t)NTOK * FF_DIM * 2);
    bf16* w2part = bufA;   // 4 x 8.39 MB spans bufA..vb (all dead by W2)
    (void)ws_size; (void)n_in; (void)in_sizes; (void)out_size;

    prep_kernel<<<12288, 256, 0, stream>>>(Wqkv, Wo_w, W1, W2,
                                           Wqkv_b, Wo_bf, W1_b, W2_b);

    layernorm_kernel<<<NTOK, 256, 0, stream>>>(x, scale1, shift1, bufA);

    // merged QKV projection: N=3072, 256^2 pipelined kernel (192 blocks)
    gemm2_nt<0><<<dim3(3072 / 256, NTOK / 256), 512, 0, stream>>>(
        bufA, Wqkv_b, nullptr, qb, kb, vb, NTOK, 3072, D_MODEL, D_MODEL);

    transpose_v<<<1024, 256, 0, stream>>>(vb, vtb);

    attn_kernel<<<512, 512, 0, stream>>>(qb, kb, vtb, bufA);

    // Wo: x1 = x + attn*Wo^T + Wo_b   (old 128^2 kernel: N=1024 -> 256 blocks)
    gemm_nt<1><<<dim3(D_MODEL / 128, NTOK / 128), 256, 0, stream>>>(
        bufA, Wo_bf, Wo_b, x, x1, nullptr, nullptr, nullptr, NTOK, D_MODEL, D_MODEL, D_MODEL);

    layernorm_kernel<<<NTOK, 256, 0, stream>>>(x1, scale2, shift2, qb);

    // W1 + gelu: 256 blocks, one per CU
    gemm2_nt<2><<<dim3(FF_DIM / 256, NTOK / 256), 512, 0, stream>>>(
        qb, W1_b, b1, mbuf, nullptr, nullptr, NTOK, FF_DIM, D_MODEL, D_MODEL);

    // W2 split-K=4 (256 blocks), bf16 partials, then combine
    gemm2_nt<6><<<dim3(D_MODEL / 256, NTOK / 256, 4), 512, 0, stream>>>(
        mbuf, W2_b, nullptr, w2part, nullptr, nullptr, NTOK, D_MODEL, FF_DIM, FF_DIM / 4);

    combine_w2<<<NTOK * D_MODEL / 1024, 256, 0, stream>>>(w2part, x1, b2, out);
}